// Round 5
// baseline (250.483 us; speedup 1.0000x reference)
//
#include <hip/hip_runtime.h>
#include <math.h>

#define B_SZ 4
#define C_IN 64
#define HW_ 576
#define NBLK 256
#define NTHR 576

typedef _Float16 h2 __attribute__((ext_vector_type(2)));
typedef _Float16 h4 __attribute__((ext_vector_type(4)));

static __device__ __forceinline__ h2 lo2(h4 v) { return __builtin_shufflevector(v, v, 0, 1); }
static __device__ __forceinline__ h2 hi2(h4 v) { return __builtin_shufflevector(v, v, 2, 3); }

static __device__ __forceinline__ float dot2(h2 a, h2 b, float c) {
#if __has_builtin(__builtin_amdgcn_fdot2)
  return __builtin_amdgcn_fdot2(a, b, c, false);
#else
  return c + (float)a.x * (float)b.x + (float)a.y * (float)b.y;
#endif
}

// Packed plane: per (b, icp) 26 rows x 28 cols of h2 (channel pair), halo=0,
// entry (r,e) = pixel (y=r-1, x=e-1). Cols 26,27 are never read.
#define PPLANE 728                    // 26*28
#define XH_N   (B_SZ * 32 * PPLANE)   // 93184
#define WQH_N  (192 * 32 * 9)         // 55296: ((g*32+icp)*3+o)*9+t, g<64
#define WOH_N  (64 * 32 * 9)          // 18432: (oc*32+icp)*9+t

// Device-wide barrier. Safe without cooperative launch: 256 blocks x 9 waves
// each; a CU can host 3 such blocks (32-wave cap, LDS 8KB/block), so HW
// dispatches ALL blocks immediately -> co-residency guaranteed by capacity.
// Monotone counter (memset to 0 per launch); fences give agent-scope
// release/acquire (L2 writeback + invalidate) across non-coherent XCD L2s.
static __device__ __forceinline__ void gbar(unsigned* cnt, unsigned target) {
  __syncthreads();
  if (threadIdx.x == 0) {
    __threadfence();  // release: drain + write back L2
    __hip_atomic_fetch_add(cnt, 1u, __ATOMIC_ACQ_REL, __HIP_MEMORY_SCOPE_AGENT);
    while (__hip_atomic_load(cnt, __ATOMIC_ACQUIRE, __HIP_MEMORY_SCOPE_AGENT) < target) {
      __builtin_amdgcn_s_sleep(2);
    }
  }
  __syncthreads();
  __threadfence();    // acquire: invalidate stale L1/L2 before reading peers' data
}

__global__ __launch_bounds__(NTHR)
void fused_kernel(const float* __restrict__ x, const float* __restrict__ gamma,
                  const float* __restrict__ beta, const float* __restrict__ wq,
                  const float* __restrict__ wo, float* __restrict__ out,
                  float* __restrict__ A, float* __restrict__ Bc,
                  h2* __restrict__ xh, h2* __restrict__ wqh,
                  h2* __restrict__ woh, h2* __restrict__ outv,
                  float* __restrict__ qkv, unsigned* __restrict__ barcnt) {
  const int bid = blockIdx.x;
  const int tid = threadIdx.x;
  __shared__ __align__(16) char smem[8192];

  // ---------------- P1: BN batch stats -> A,Bc (blocks 0..63) --------------
  if (bid < 64) {
    const int c = bid;
    float s = 0.f, ss = 0.f;
    for (int j = tid; j < B_SZ * HW_; j += NTHR) {
      int b = j / HW_, i = j - b * HW_;
      float v = x[(b * C_IN + c) * HW_ + i];
      s += v; ss = fmaf(v, v, ss);
    }
#pragma unroll
    for (int off = 32; off > 0; off >>= 1) {
      s += __shfl_down(s, off);
      ss += __shfl_down(ss, off);
    }
    float* red = (float*)smem;
    if ((tid & 63) == 0) { red[tid >> 6] = s; red[16 + (tid >> 6)] = ss; }
    __syncthreads();
    if (tid == 0) {
      s = 0.f; ss = 0.f;
      for (int w = 0; w < 9; ++w) { s += red[w]; ss += red[16 + w]; }
      const float inv_n = 1.f / (B_SZ * HW_);
      float mean = s * inv_n;
      float var  = ss * inv_n - mean * mean;
      float a = rsqrtf(var + 1e-5f) * gamma[c];
      A[c]  = a;
      Bc[c] = fmaf(-mean, a, beta[c]);
    }
  }
  gbar(barcnt, 1 * NBLK);

  // ---------------- P2: pack xn + weights to f16 ---------------------------
  for (int t = bid * NTHR + tid; t < XH_N + WQH_N + WOH_N; t += NBLK * NTHR) {
    if (t < XH_N) {
      int b = t / (32 * PPLANE);
      int r0 = t - b * (32 * PPLANE);
      int icp = r0 / PPLANE;
      int rr = r0 - icp * PPLANE;
      int rrow = rr / 28, e = rr - rrow * 28;
      int yy = rrow - 1, xx = e - 1;
      float f0 = 0.f, f1 = 0.f;
      if ((unsigned)yy < 24u && (unsigned)xx < 24u) {
        int c0 = icp * 2;
        int base = ((b * C_IN + c0) * HW_) + yy * 24 + xx;
        f0 = fmaf(x[base], A[c0], Bc[c0]);
        f1 = fmaf(x[base + HW_], A[c0 + 1], Bc[c0 + 1]);
      }
      h2 v; v.x = (_Float16)f0; v.y = (_Float16)f1;
      xh[t] = v;
    } else if (t < XH_N + WQH_N) {
      int t0 = t - XH_N;
      int tt = t0 % 9; int r = t0 / 9;
      int o = r % 3; r /= 3;
      int icp = r % 32; int g = r / 32;
      int oc = g * 3 + o, ic = icp * 2;
      h2 v;
      v.x = (_Float16)wq[(oc * C_IN + ic) * 9 + tt];
      v.y = (_Float16)wq[(oc * C_IN + ic + 1) * 9 + tt];
      wqh[t0] = v;
    } else {
      int t0 = t - XH_N - WQH_N;
      int tt = t0 % 9; int r = t0 / 9;
      int icp = r % 32; int oc = r / 32;
      int ic = icp * 2;
      h2 v;  // scale by 4096: dodge f16 subnormals (w_out ~ 7e-5)
      v.x = (_Float16)(wo[(oc * C_IN + ic) * 9 + tt] * 4096.f);
      v.y = (_Float16)(wo[(oc * C_IN + ic + 1) * 9 + tt] * 4096.f);
      woh[t0] = v;
    }
  }
  gbar(barcnt, 2 * NBLK);

  // ---------------- P3: qkv conv. block=(b,g), OCG=3, in-block split-K -----
  {
    const int b = bid >> 6;
    const int g = bid & 63;
    const int sub = tid / 288;          // K-half
    const int r = tid - sub * 288;      // 0..287: y=r/12, x0=2*(r%12)
    const int y = r / 12, x0 = (r % 12) * 2;

    h2* Wl = (h2*)smem;                 // [32 icp][28 h2] (27 used, 16B rows)
    for (int j = tid; j < 864; j += NTHR) {
      int icp = j / 27, rem = j - icp * 27;
      Wl[icp * 28 + rem] = wqh[g * 864 + j];
    }
    __syncthreads();

    float acc[3][2] = {{0.f, 0.f}, {0.f, 0.f}, {0.f, 0.f}};
    const int icp0 = sub * 16;
    for (int i = 0; i < 16; ++i) {
      const int icp = icp0 + i;
      const h2* wrow = Wl + icp * 28;
      h2 W[27];
#pragma unroll
      for (int tt = 0; tt < 27; ++tt) W[tt] = wrow[tt];
      const h2* dp = xh + ((size_t)(b * 32 + icp) * PPLANE + y * 28 + x0);
      h4 r0a = *(const h4*)(dp);      h4 r0b = *(const h4*)(dp + 2);
      h4 r1a = *(const h4*)(dp + 28); h4 r1b = *(const h4*)(dp + 30);
      h4 r2a = *(const h4*)(dp + 56); h4 r2b = *(const h4*)(dp + 58);
#pragma unroll
      for (int o = 0; o < 3; ++o) {
        const h2* w9 = W + o * 9;
        float a0 = acc[o][0], a1 = acc[o][1];
        a0 = dot2(lo2(r0a), w9[0], a0);  a1 = dot2(hi2(r0a), w9[0], a1);
        a0 = dot2(hi2(r0a), w9[1], a0);  a1 = dot2(lo2(r0b), w9[1], a1);
        a0 = dot2(lo2(r0b), w9[2], a0);  a1 = dot2(hi2(r0b), w9[2], a1);
        a0 = dot2(lo2(r1a), w9[3], a0);  a1 = dot2(hi2(r1a), w9[3], a1);
        a0 = dot2(hi2(r1a), w9[4], a0);  a1 = dot2(lo2(r1b), w9[4], a1);
        a0 = dot2(lo2(r1b), w9[5], a0);  a1 = dot2(hi2(r1b), w9[5], a1);
        a0 = dot2(lo2(r2a), w9[6], a0);  a1 = dot2(hi2(r2a), w9[6], a1);
        a0 = dot2(hi2(r2a), w9[7], a0);  a1 = dot2(lo2(r2b), w9[7], a1);
        a0 = dot2(lo2(r2b), w9[8], a0);  a1 = dot2(hi2(r2b), w9[8], a1);
        acc[o][0] = a0; acc[o][1] = a1;
      }
    }
    __syncthreads();                    // done with Wl before overlay
    float* cb = (float*)smem;           // [3][288][2]
    if (sub == 1) {
#pragma unroll
      for (int o = 0; o < 3; ++o) {
        cb[(o * 288 + r) * 2 + 0] = acc[o][0];
        cb[(o * 288 + r) * 2 + 1] = acc[o][1];
      }
    }
    __syncthreads();
    if (sub == 0) {
#pragma unroll
      for (int o = 0; o < 3; ++o) {
        float2 v = make_float2(acc[o][0] + cb[(o * 288 + r) * 2 + 0],
                               acc[o][1] + cb[(o * 288 + r) * 2 + 1]);
        *(float2*)(qkv + ((size_t)(b * 192 + g * 3 + o) * HW_ + y * 24 + x0)) = v;
      }
    }
  }
  gbar(barcnt, 3 * NBLK);

  // ---------------- P4: rank-1 attention, write packed f16 out_v -----------
  {
    const int b = bid >> 6, c = bid & 63;
    float2* kvs = (float2*)smem;              // 4608 B
    float* red = (float*)(smem + 4608);       // 20 floats
    const float* qp = qkv + (size_t)(b * 192 + c) * HW_;
    float q  = qp[tid];
    float kk = qp[64 * HW_ + tid];
    float vv = qp[128 * HW_ + tid];
    kvs[tid] = make_float2(kk, vv);
    float kmax = kk, kmin = kk;
#pragma unroll
    for (int off = 32; off > 0; off >>= 1) {
      kmax = fmaxf(kmax, __shfl_down(kmax, off));
      kmin = fminf(kmin, __shfl_down(kmin, off));
    }
    if ((tid & 63) == 0) { red[tid >> 6] = kmax; red[10 + (tid >> 6)] = kmin; }
    __syncthreads();
    kmax = red[0]; kmin = red[10];
#pragma unroll
    for (int w = 1; w < 9; ++w) {
      kmax = fmaxf(kmax, red[w]); kmin = fminf(kmin, red[10 + w]);
    }
    const float scale_l2e = 0.125f * 1.44269504088896341f;
    const float s = q * scale_l2e;
    const float m = (s >= 0.f) ? s * kmax : s * kmin;
    float n0 = 0.f, n1 = 0.f, n2 = 0.f, n3 = 0.f;
    float d0 = 0.f, d1 = 0.f, d2 = 0.f, d3 = 0.f;
    for (int i = 0; i < HW_; i += 4) {
      float4 p0 = *reinterpret_cast<const float4*>(&kvs[i]);
      float4 p1 = *reinterpret_cast<const float4*>(&kvs[i + 2]);
      float e0 = __builtin_amdgcn_exp2f(fmaf(s, p0.x, -m));
      float e1 = __builtin_amdgcn_exp2f(fmaf(s, p0.z, -m));
      float e2 = __builtin_amdgcn_exp2f(fmaf(s, p1.x, -m));
      float e3 = __builtin_amdgcn_exp2f(fmaf(s, p1.z, -m));
      d0 += e0; n0 = fmaf(e0, p0.y, n0);
      d1 += e1; n1 = fmaf(e1, p0.w, n1);
      d2 += e2; n2 = fmaf(e2, p1.y, n2);
      d3 += e3; n3 = fmaf(e3, p1.w, n3);
    }
    float rr = (n0 + n1 + n2 + n3) / (d0 + d1 + d2 + d3);

    const int icp = c >> 1, hc = c & 1;
    _Float16* plane = reinterpret_cast<_Float16*>(outv + ((size_t)(b * 32) + icp) * PPLANE);
    const int yy = tid / 24, xx = tid - yy * 24;
    plane[((yy + 1) * 28 + (xx + 1)) * 2 + hc] = (_Float16)rr;
    if (tid < 100) {  // zero halo
      int rrow, e;
      if (tid < 26)      { rrow = 0;            e = tid; }
      else if (tid < 52) { rrow = 25;           e = tid - 26; }
      else if (tid < 76) { rrow = tid - 52 + 1; e = 0; }
      else               { rrow = tid - 76 + 1; e = 25; }
      plane[(rrow * 28 + e) * 2 + hc] = (_Float16)0.f;
    }
  }
  gbar(barcnt, 4 * NBLK);

  // ---------------- P5: out conv (OCG=1) + residual + final store ----------
  {
    const int b = bid >> 6, oc = bid & 63;
    const int sub = tid / 288;
    const int r = tid - sub * 288;
    const int y = r / 12, x0 = (r % 12) * 2;

    h2* Wl = (h2*)smem;                 // [32 icp][12 h2] (9 used)
    for (int j = tid; j < 288; j += NTHR) {
      int icp = j / 9, rem = j - icp * 9;
      Wl[icp * 12 + rem] = woh[oc * 288 + j];
    }
    __syncthreads();

    float a0 = 0.f, a1 = 0.f;
    const int icp0 = sub * 16;
    for (int i = 0; i < 16; ++i) {
      const int icp = icp0 + i;
      const h2* w9r = Wl + icp * 12;
      h2 W[9];
#pragma unroll
      for (int tt = 0; tt < 9; ++tt) W[tt] = w9r[tt];
      const h2* dp = outv + ((size_t)(b * 32 + icp) * PPLANE + y * 28 + x0);
      h4 r0a = *(const h4*)(dp);      h4 r0b = *(const h4*)(dp + 2);
      h4 r1a = *(const h4*)(dp + 28); h4 r1b = *(const h4*)(dp + 30);
      h4 r2a = *(const h4*)(dp + 56); h4 r2b = *(const h4*)(dp + 58);
      a0 = dot2(lo2(r0a), W[0], a0);  a1 = dot2(hi2(r0a), W[0], a1);
      a0 = dot2(hi2(r0a), W[1], a0);  a1 = dot2(lo2(r0b), W[1], a1);
      a0 = dot2(lo2(r0b), W[2], a0);  a1 = dot2(hi2(r0b), W[2], a1);
      a0 = dot2(lo2(r1a), W[3], a0);  a1 = dot2(hi2(r1a), W[3], a1);
      a0 = dot2(hi2(r1a), W[4], a0);  a1 = dot2(lo2(r1b), W[4], a1);
      a0 = dot2(lo2(r1b), W[5], a0);  a1 = dot2(hi2(r1b), W[5], a1);
      a0 = dot2(lo2(r2a), W[6], a0);  a1 = dot2(hi2(r2a), W[6], a1);
      a0 = dot2(hi2(r2a), W[7], a0);  a1 = dot2(lo2(r2b), W[7], a1);
      a0 = dot2(lo2(r2b), W[8], a0);  a1 = dot2(hi2(r2b), W[8], a1);
    }
    __syncthreads();
    float* cb = (float*)smem;           // [288][2]
    if (sub == 1) { cb[r * 2] = a0; cb[r * 2 + 1] = a1; }
    __syncthreads();
    if (sub == 0) {
      size_t idx = ((size_t)(b * C_IN + oc) * HW_) + y * 24 + x0;
      float2 xr = *reinterpret_cast<const float2*>(x + idx);
      const float inv = 1.f / 4096.f;
      float2 v;
      v.x = fmaf(a0 + cb[r * 2],     inv, xr.x);
      v.y = fmaf(a1 + cb[r * 2 + 1], inv, xr.y);
      *reinterpret_cast<float2*>(out + idx) = v;
    }
  }
}

// ---------------- launch ---------------------------------------------------
extern "C" void kernel_launch(void* const* d_in, const int* in_sizes, int n_in,
                              void* d_out, int out_size, void* d_ws, size_t ws_size,
                              hipStream_t stream) {
  const float* x     = (const float*)d_in[0];
  const float* gamma = (const float*)d_in[1];
  const float* beta  = (const float*)d_in[2];
  const float* w_qkv = (const float*)d_in[3];
  const float* w_out = (const float*)d_in[4];
  float* out = (float*)d_out;

  float* A   = (float*)d_ws;
  float* Bc  = A + 64;
  h2* xh     = (h2*)(Bc + 64);
  h2* wqh    = xh + XH_N;
  h2* woh    = wqh + WQH_N;
  h2* outv   = woh + WOH_N;
  float* qkv = (float*)(outv + XH_N);
  unsigned* barcnt = (unsigned*)(qkv + (size_t)B_SZ * 192 * HW_);

  hipMemsetAsync(barcnt, 0, 128, stream);
  fused_kernel<<<NBLK, NTHR, 0, stream>>>(x, gamma, beta, w_qkv, w_out, out,
                                          A, Bc, xh, wqh, woh, outv, qkv, barcnt);
}

// Round 6
// 41.886 us; speedup vs baseline: 5.9800x; 5.9800x over previous
//
#include <hip/hip_runtime.h>
#include <math.h>

#define B_SZ 4
#define C_IN 64
#define HW_ 576
#define PPLANE 728                    // 26*28 padded plane of h2 (channel pair)
#define XH_N   (B_SZ * 32 * PPLANE)   // 93184
#define WQH_N  (192 * 32 * 9)         // 55296: ((g*32+icp)*3+o)*9+t, g<64
#define WOH_N  (64 * 32 * 9)          // 18432: (oc*32+icp)*9+t

typedef _Float16 h2 __attribute__((ext_vector_type(2)));
typedef _Float16 h4 __attribute__((ext_vector_type(4)));

static __device__ __forceinline__ h2 lo2(h4 v) { return __builtin_shufflevector(v, v, 0, 1); }
static __device__ __forceinline__ h2 hi2(h4 v) { return __builtin_shufflevector(v, v, 2, 3); }

static __device__ __forceinline__ float dot2(h2 a, h2 b, float c) {
#if __has_builtin(__builtin_amdgcn_fdot2)
  return __builtin_amdgcn_fdot2(a, b, c, false);
#else
  return c + (float)a.x * (float)b.x + (float)a.y * (float)b.y;
#endif
}

// ---------------- K1: BN stats (redundant per block) + pack x & weights ----
// Blocks 0..127: (b = bid/32, icp = bid%32). Compute stats for channels
// 2icp,2icp+1 over the full batch (4x redundancy), then pack own plane.
// Blocks 128..255: pack 576 weight h2 entries each (73728 total, exact).
__global__ __launch_bounds__(256)
void stats_pack_kernel(const float* __restrict__ x, const float* __restrict__ gamma,
                       const float* __restrict__ beta, const float* __restrict__ wq,
                       const float* __restrict__ wo, h2* __restrict__ xh,
                       h2* __restrict__ wqh, h2* __restrict__ woh) {
  const int bid = blockIdx.x, tid = threadIdx.x;
  if (bid < 128) {
    const int icp = bid & 31, b = bid >> 5;
    __shared__ float rs[4], rss[4], ab[4];
    // threads 0..127 -> channel 2icp (waves 0,1); 128..255 -> 2icp+1 (waves 2,3)
    const int c = icp * 2 + (tid >> 7);
    float s = 0.f, ss = 0.f;
    for (int i = (tid & 127); i < B_SZ * HW_; i += 128) {
      int b2 = i / HW_, px = i - b2 * HW_;
      float v = x[(b2 * C_IN + c) * HW_ + px];
      s += v; ss = fmaf(v, v, ss);
    }
#pragma unroll
    for (int off = 32; off > 0; off >>= 1) {
      s += __shfl_down(s, off); ss += __shfl_down(ss, off);
    }
    if ((tid & 63) == 0) { rs[tid >> 6] = s; rss[tid >> 6] = ss; }
    __syncthreads();
    if (tid < 2) {
      float S = rs[tid * 2] + rs[tid * 2 + 1], SS = rss[tid * 2] + rss[tid * 2 + 1];
      const float inv_n = 1.f / (B_SZ * HW_);
      float mean = S * inv_n;
      float var  = SS * inv_n - mean * mean;
      float a = rsqrtf(var + 1e-5f) * gamma[icp * 2 + tid];
      ab[tid * 2] = a;
      ab[tid * 2 + 1] = fmaf(-mean, a, beta[icp * 2 + tid]);
    }
    __syncthreads();
    const float a0 = ab[0], b0 = ab[1], a1 = ab[2], b1 = ab[3];
    h2* plane = xh + (size_t)(b * 32 + icp) * PPLANE;
    const float* src0 = x + (size_t)(b * C_IN + icp * 2) * HW_;
    for (int e = tid; e < PPLANE; e += 256) {
      int rrow = e / 28, ecol = e - rrow * 28;
      int yy = rrow - 1, xx = ecol - 1;
      float f0 = 0.f, f1 = 0.f;
      if ((unsigned)yy < 24u && (unsigned)xx < 24u) {
        f0 = fmaf(src0[yy * 24 + xx],       a0, b0);
        f1 = fmaf(src0[HW_ + yy * 24 + xx], a1, b1);
      }
      h2 v; v.x = (_Float16)f0; v.y = (_Float16)f1;
      plane[e] = v;
    }
  } else {
    const int base = (bid - 128) * 576;
    for (int t = base + tid; t < base + 576; t += 256) {
      if (t < WQH_N) {
        int tt = t % 9; int r = t / 9;
        int o = r % 3; r /= 3;
        int icp = r % 32; int g = r / 32;
        int oc = g * 3 + o, ic = icp * 2;
        h2 v;
        v.x = (_Float16)wq[(oc * C_IN + ic) * 9 + tt];
        v.y = (_Float16)wq[(oc * C_IN + ic + 1) * 9 + tt];
        wqh[t] = v;
      } else {
        int t0 = t - WQH_N;
        int tt = t0 % 9; int r = t0 / 9;
        int icp = r % 32; int oc = r / 32;
        int ic = icp * 2;
        h2 v;  // scale 4096: dodge f16 subnormals (w_out ~ 7e-5)
        v.x = (_Float16)(wo[(oc * C_IN + ic) * 9 + tt] * 4096.f);
        v.y = (_Float16)(wo[(oc * C_IN + ic + 1) * 9 + tt] * 4096.f);
        woh[t0] = v;
      }
    }
  }
}

// ---------------- K2: qkv conv, block=(b,g), OCG=3, in-block split-K -------
__global__ __launch_bounds__(576)
void conv_qkv_kernel(const h2* __restrict__ xh, const h2* __restrict__ wqh,
                     float* __restrict__ qkv) {
  const int bid = blockIdx.x, tid = threadIdx.x;
  const int b = bid >> 6, g = bid & 63;
  const int sub = tid / 288;          // K-half
  const int r = tid - sub * 288;      // y=r/12, x0=2*(r%12)
  const int y = r / 12, x0 = (r % 12) * 2;
  __shared__ __align__(16) char smem[8192];

  h2* Wl = (h2*)smem;                 // [32 icp][28 h2] (27 used)
  for (int j = tid; j < 864; j += 576) {
    int icp = j / 27, rem = j - icp * 27;
    Wl[icp * 28 + rem] = wqh[g * 864 + j];
  }
  __syncthreads();

  float acc[3][2] = {{0.f, 0.f}, {0.f, 0.f}, {0.f, 0.f}};
  const int icp0 = sub * 16;
  for (int i = 0; i < 16; ++i) {
    const int icp = icp0 + i;
    const h2* wrow = Wl + icp * 28;
    h2 W[27];
#pragma unroll
    for (int tt = 0; tt < 27; ++tt) W[tt] = wrow[tt];
    const h2* dp = xh + ((size_t)(b * 32 + icp) * PPLANE + y * 28 + x0);
    h4 r0a = *(const h4*)(dp);      h4 r0b = *(const h4*)(dp + 2);
    h4 r1a = *(const h4*)(dp + 28); h4 r1b = *(const h4*)(dp + 30);
    h4 r2a = *(const h4*)(dp + 56); h4 r2b = *(const h4*)(dp + 58);
#pragma unroll
    for (int o = 0; o < 3; ++o) {
      const h2* w9 = W + o * 9;
      float a0 = acc[o][0], a1 = acc[o][1];
      a0 = dot2(lo2(r0a), w9[0], a0);  a1 = dot2(hi2(r0a), w9[0], a1);
      a0 = dot2(hi2(r0a), w9[1], a0);  a1 = dot2(lo2(r0b), w9[1], a1);
      a0 = dot2(lo2(r0b), w9[2], a0);  a1 = dot2(hi2(r0b), w9[2], a1);
      a0 = dot2(lo2(r1a), w9[3], a0);  a1 = dot2(hi2(r1a), w9[3], a1);
      a0 = dot2(hi2(r1a), w9[4], a0);  a1 = dot2(lo2(r1b), w9[4], a1);
      a0 = dot2(lo2(r1b), w9[5], a0);  a1 = dot2(hi2(r1b), w9[5], a1);
      a0 = dot2(lo2(r2a), w9[6], a0);  a1 = dot2(hi2(r2a), w9[6], a1);
      a0 = dot2(hi2(r2a), w9[7], a0);  a1 = dot2(lo2(r2b), w9[7], a1);
      a0 = dot2(lo2(r2b), w9[8], a0);  a1 = dot2(hi2(r2b), w9[8], a1);
      acc[o][0] = a0; acc[o][1] = a1;
    }
  }
  __syncthreads();
  float* cb = (float*)smem;           // [3][288][2]
  if (sub == 1) {
#pragma unroll
    for (int o = 0; o < 3; ++o) {
      cb[(o * 288 + r) * 2 + 0] = acc[o][0];
      cb[(o * 288 + r) * 2 + 1] = acc[o][1];
    }
  }
  __syncthreads();
  if (sub == 0) {
#pragma unroll
    for (int o = 0; o < 3; ++o) {
      float2 v = make_float2(acc[o][0] + cb[(o * 288 + r) * 2 + 0],
                             acc[o][1] + cb[(o * 288 + r) * 2 + 1]);
      *(float2*)(qkv + ((size_t)(b * 192 + g * 3 + o) * HW_ + y * 24 + x0)) = v;
    }
  }
}

// ---------------- K3: rank-1 attention, writes packed f16 out_v ------------
__global__ __launch_bounds__(576)
void attn_kernel(const float* __restrict__ qkv, h2* __restrict__ outv) {
  const int bc = blockIdx.x;
  const int b = bc >> 6, c = bc & 63;
  const int tid = threadIdx.x;
  __shared__ __align__(16) float2 kvs[HW_];
  __shared__ float red[20];
  const float* qp = qkv + (size_t)(b * 192 + c) * HW_;
  float q  = qp[tid];
  float kk = qp[64 * HW_ + tid];
  float vv = qp[128 * HW_ + tid];
  kvs[tid] = make_float2(kk, vv);
  float kmax = kk, kmin = kk;
#pragma unroll
  for (int off = 32; off > 0; off >>= 1) {
    kmax = fmaxf(kmax, __shfl_down(kmax, off));
    kmin = fminf(kmin, __shfl_down(kmin, off));
  }
  if ((tid & 63) == 0) { red[tid >> 6] = kmax; red[10 + (tid >> 6)] = kmin; }
  __syncthreads();
  kmax = red[0]; kmin = red[10];
#pragma unroll
  for (int w = 1; w < 9; ++w) {
    kmax = fmaxf(kmax, red[w]); kmin = fminf(kmin, red[10 + w]);
  }
  const float scale_l2e = 0.125f * 1.44269504088896341f;  // 1/sqrt(64)*log2(e)
  const float s = q * scale_l2e;
  const float m = (s >= 0.f) ? s * kmax : s * kmin;
  float n0 = 0.f, n1 = 0.f, n2 = 0.f, n3 = 0.f;
  float d0 = 0.f, d1 = 0.f, d2 = 0.f, d3 = 0.f;
  for (int i = 0; i < HW_; i += 4) {
    float4 p0 = *reinterpret_cast<const float4*>(&kvs[i]);
    float4 p1 = *reinterpret_cast<const float4*>(&kvs[i + 2]);
    float e0 = __builtin_amdgcn_exp2f(fmaf(s, p0.x, -m));
    float e1 = __builtin_amdgcn_exp2f(fmaf(s, p0.z, -m));
    float e2 = __builtin_amdgcn_exp2f(fmaf(s, p1.x, -m));
    float e3 = __builtin_amdgcn_exp2f(fmaf(s, p1.z, -m));
    d0 += e0; n0 = fmaf(e0, p0.y, n0);
    d1 += e1; n1 = fmaf(e1, p0.w, n1);
    d2 += e2; n2 = fmaf(e2, p1.y, n2);
    d3 += e3; n3 = fmaf(e3, p1.w, n3);
  }
  float rr = (n0 + n1 + n2 + n3) / (d0 + d1 + d2 + d3);

  const int icp = c >> 1, hc = c & 1;
  _Float16* plane = reinterpret_cast<_Float16*>(outv + ((size_t)(b * 32) + icp) * PPLANE);
  const int yy = tid / 24, xx = tid - yy * 24;
  plane[((yy + 1) * 28 + (xx + 1)) * 2 + hc] = (_Float16)rr;
  if (tid < 100) {  // zero halo (cols 26,27 never read)
    int rrow, e;
    if (tid < 26)      { rrow = 0;            e = tid; }
    else if (tid < 52) { rrow = 25;           e = tid - 26; }
    else if (tid < 76) { rrow = tid - 52 + 1; e = 0; }
    else               { rrow = tid - 76 + 1; e = 25; }
    plane[(rrow * 28 + e) * 2 + hc] = (_Float16)0.f;
  }
}

// ---------------- K4: out conv (OCG=1) + residual + final store ------------
__global__ __launch_bounds__(576)
void conv_out_kernel(const h2* __restrict__ outv, const h2* __restrict__ woh,
                     const float* __restrict__ x, float* __restrict__ out) {
  const int bid = blockIdx.x, tid = threadIdx.x;
  const int b = bid >> 6, oc = bid & 63;
  const int sub = tid / 288;
  const int r = tid - sub * 288;
  const int y = r / 12, x0 = (r % 12) * 2;
  __shared__ __align__(16) char smem[4096];

  h2* Wl = (h2*)smem;                 // [32 icp][12 h2] (9 used)
  for (int j = tid; j < 288; j += 576) {
    int icp = j / 9, rem = j - icp * 9;
    Wl[icp * 12 + rem] = woh[oc * 288 + j];
  }
  __syncthreads();

  float a0 = 0.f, a1 = 0.f;
  const int icp0 = sub * 16;
  for (int i = 0; i < 16; ++i) {
    const int icp = icp0 + i;
    const h2* w9r = Wl + icp * 12;
    h2 W[9];
#pragma unroll
    for (int tt = 0; tt < 9; ++tt) W[tt] = w9r[tt];
    const h2* dp = outv + ((size_t)(b * 32 + icp) * PPLANE + y * 28 + x0);
    h4 r0a = *(const h4*)(dp);      h4 r0b = *(const h4*)(dp + 2);
    h4 r1a = *(const h4*)(dp + 28); h4 r1b = *(const h4*)(dp + 30);
    h4 r2a = *(const h4*)(dp + 56); h4 r2b = *(const h4*)(dp + 58);
    a0 = dot2(lo2(r0a), W[0], a0);  a1 = dot2(hi2(r0a), W[0], a1);
    a0 = dot2(hi2(r0a), W[1], a0);  a1 = dot2(lo2(r0b), W[1], a1);
    a0 = dot2(lo2(r0b), W[2], a0);  a1 = dot2(hi2(r0b), W[2], a1);
    a0 = dot2(lo2(r1a), W[3], a0);  a1 = dot2(hi2(r1a), W[3], a1);
    a0 = dot2(hi2(r1a), W[4], a0);  a1 = dot2(lo2(r1b), W[4], a1);
    a0 = dot2(lo2(r1b), W[5], a0);  a1 = dot2(hi2(r1b), W[5], a1);
    a0 = dot2(lo2(r2a), W[6], a0);  a1 = dot2(hi2(r2a), W[6], a1);
    a0 = dot2(hi2(r2a), W[7], a0);  a1 = dot2(lo2(r2b), W[7], a1);
    a0 = dot2(lo2(r2b), W[8], a0);  a1 = dot2(hi2(r2b), W[8], a1);
  }
  __syncthreads();
  float* cb = (float*)smem;           // [288][2]
  if (sub == 1) { cb[r * 2] = a0; cb[r * 2 + 1] = a1; }
  __syncthreads();
  if (sub == 0) {
    size_t idx = ((size_t)(b * C_IN + oc) * HW_) + y * 24 + x0;
    float2 xr = *reinterpret_cast<const float2*>(x + idx);
    const float inv = 1.f / 4096.f;
    float2 v;
    v.x = fmaf(a0 + cb[r * 2],     inv, xr.x);
    v.y = fmaf(a1 + cb[r * 2 + 1], inv, xr.y);
    *reinterpret_cast<float2*>(out + idx) = v;
  }
}

// ---------------- launch ---------------------------------------------------
extern "C" void kernel_launch(void* const* d_in, const int* in_sizes, int n_in,
                              void* d_out, int out_size, void* d_ws, size_t ws_size,
                              hipStream_t stream) {
  const float* x     = (const float*)d_in[0];
  const float* gamma = (const float*)d_in[1];
  const float* beta  = (const float*)d_in[2];
  const float* w_qkv = (const float*)d_in[3];
  const float* w_out = (const float*)d_in[4];
  float* out = (float*)d_out;

  h2* xh     = (h2*)d_ws;
  h2* wqh    = xh + XH_N;
  h2* woh    = wqh + WQH_N;
  h2* outv   = woh + WOH_N;
  float* qkv = (float*)(outv + XH_N);

  stats_pack_kernel<<<256, 256, 0, stream>>>(x, gamma, beta, w_qkv, w_out, xh, wqh, woh);
  conv_qkv_kernel<<<256, 576, 0, stream>>>(xh, wqh, qkv);
  attn_kernel<<<256, 576, 0, stream>>>(qkv, outv);
  conv_out_kernel<<<256, 576, 0, stream>>>(outv, woh, x, out);
}

// Round 7
// 39.616 us; speedup vs baseline: 6.3228x; 1.0573x over previous
//
#include <hip/hip_runtime.h>
#include <math.h>

#define B_SZ 4
#define C_IN 64
#define HW_ 576
#define PPLANE 728                    // 26*28 padded plane of h2 (channel pair)
#define XH_N   (B_SZ * 32 * PPLANE)   // 93184
#define WQH_N  (192 * 32 * 9)         // 55296: ((g*32+icp)*3+o)*9+t, oc=g+64*o
#define WOH_N  (64 * 32 * 9)          // 18432: (oc*32+icp)*9+t

typedef _Float16 h2 __attribute__((ext_vector_type(2)));
typedef _Float16 h4 __attribute__((ext_vector_type(4)));

static __device__ __forceinline__ h2 lo2(h4 v) { return __builtin_shufflevector(v, v, 0, 1); }
static __device__ __forceinline__ h2 hi2(h4 v) { return __builtin_shufflevector(v, v, 2, 3); }

static __device__ __forceinline__ float dot2(h2 a, h2 b, float c) {
#if __has_builtin(__builtin_amdgcn_fdot2)
  return __builtin_amdgcn_fdot2(a, b, c, false);
#else
  return c + (float)a.x * (float)b.x + (float)a.y * (float)b.y;
#endif
}

// ---------------- K1: BN stats (redundant per block) + pack x & weights ----
__global__ __launch_bounds__(256)
void stats_pack_kernel(const float* __restrict__ x, const float* __restrict__ gamma,
                       const float* __restrict__ beta, const float* __restrict__ wq,
                       const float* __restrict__ wo, h2* __restrict__ xh,
                       h2* __restrict__ wqh, h2* __restrict__ woh) {
  const int bid = blockIdx.x, tid = threadIdx.x;
  if (bid < 128) {
    const int icp = bid & 31, b = bid >> 5;
    __shared__ float rs[4], rss[4], ab[4];
    const int c = icp * 2 + (tid >> 7);
    float s = 0.f, ss = 0.f;
    for (int i = (tid & 127); i < B_SZ * HW_; i += 128) {
      int b2 = i / HW_, px = i - b2 * HW_;
      float v = x[(b2 * C_IN + c) * HW_ + px];
      s += v; ss = fmaf(v, v, ss);
    }
#pragma unroll
    for (int off = 32; off > 0; off >>= 1) {
      s += __shfl_down(s, off); ss += __shfl_down(ss, off);
    }
    if ((tid & 63) == 0) { rs[tid >> 6] = s; rss[tid >> 6] = ss; }
    __syncthreads();
    if (tid < 2) {
      float S = rs[tid * 2] + rs[tid * 2 + 1], SS = rss[tid * 2] + rss[tid * 2 + 1];
      const float inv_n = 1.f / (B_SZ * HW_);
      float mean = S * inv_n;
      float var  = SS * inv_n - mean * mean;
      float a = rsqrtf(var + 1e-5f) * gamma[icp * 2 + tid];
      ab[tid * 2] = a;
      ab[tid * 2 + 1] = fmaf(-mean, a, beta[icp * 2 + tid]);
    }
    __syncthreads();
    const float a0 = ab[0], b0 = ab[1], a1 = ab[2], b1 = ab[3];
    h2* plane = xh + (size_t)(b * 32 + icp) * PPLANE;
    const float* src0 = x + (size_t)(b * C_IN + icp * 2) * HW_;
    for (int e = tid; e < PPLANE; e += 256) {
      int rrow = e / 28, ecol = e - rrow * 28;
      int yy = rrow - 1, xx = ecol - 1;
      float f0 = 0.f, f1 = 0.f;
      if ((unsigned)yy < 24u && (unsigned)xx < 24u) {
        f0 = fmaf(src0[yy * 24 + xx],       a0, b0);
        f1 = fmaf(src0[HW_ + yy * 24 + xx], a1, b1);
      }
      h2 v; v.x = (_Float16)f0; v.y = (_Float16)f1;
      plane[e] = v;
    }
  } else {
    const int base = (bid - 128) * 576;
    for (int t = base + tid; t < base + 576; t += 256) {
      if (t < WQH_N) {
        int tt = t % 9; int r = t / 9;
        int o = r % 3; r /= 3;
        int icp = r % 32; int g = r / 32;
        int oc = g + 64 * o, ic = icp * 2;   // q/k/v of channel g in one block
        h2 v;
        v.x = (_Float16)wq[(oc * C_IN + ic) * 9 + tt];
        v.y = (_Float16)wq[(oc * C_IN + ic + 1) * 9 + tt];
        wqh[t] = v;
      } else {
        int t0 = t - WQH_N;
        int tt = t0 % 9; int r = t0 / 9;
        int icp = r % 32; int oc = r / 32;
        int ic = icp * 2;
        h2 v;  // scale 4096: dodge f16 subnormals (w_out ~ 7e-5)
        v.x = (_Float16)(wo[(oc * C_IN + ic) * 9 + tt] * 4096.f);
        v.y = (_Float16)(wo[(oc * C_IN + ic + 1) * 9 + tt] * 4096.f);
        woh[t0] = v;
      }
    }
  }
}

// ---------------- K2: fused qkv conv + rank-1 attention, block=(b,c) -------
// Conv phase: 576 thr = 2 K-halves x 288 pixel-pairs, OCG=3 with
// oc = {c, 64+c, 128+c}. Combine in LDS -> q,k,v planes stay in LDS.
// Attention phase: thread tid = pixel tid, softmax over 576 (k,v).
__global__ __launch_bounds__(576)
void qkv_attn_kernel(const h2* __restrict__ xh, const h2* __restrict__ wqh,
                     h2* __restrict__ outv) {
  const int bid = blockIdx.x, tid = threadIdx.x;
  const int b = bid >> 6, c = bid & 63;
  const int sub = tid / 288;
  const int r = tid - sub * 288;
  const int y = r / 12, x0 = (r % 12) * 2;

  __shared__ __align__(16) char smem[13904];
  h2*    Wl  = (h2*)smem;               // [32][28] h2, 3584 B (conv phase)
  float* cb  = (float*)smem;            // [3][288][2] f32, 6912 B (combine)
  float2* kvs = (float2*)(smem + 6912); // 576 float2, 4608 B
  float* qs  = (float*)(smem + 11520);  // 576 f32, 2304 B
  float* red = (float*)(smem + 13824);  // 20 f32

  for (int j = tid; j < 864; j += 576) {
    int icp = j / 27, rem = j - icp * 27;
    Wl[icp * 28 + rem] = wqh[c * 864 + j];
  }
  __syncthreads();

  float acc[3][2] = {{0.f, 0.f}, {0.f, 0.f}, {0.f, 0.f}};
  const int icp0 = sub * 16;
  for (int i = 0; i < 16; ++i) {
    const int icp = icp0 + i;
    const h2* wrow = Wl + icp * 28;
    h2 W[27];
#pragma unroll
    for (int tt = 0; tt < 27; ++tt) W[tt] = wrow[tt];
    const h2* dp = xh + ((size_t)(b * 32 + icp) * PPLANE + y * 28 + x0);
    h4 r0a = *(const h4*)(dp);      h4 r0b = *(const h4*)(dp + 2);
    h4 r1a = *(const h4*)(dp + 28); h4 r1b = *(const h4*)(dp + 30);
    h4 r2a = *(const h4*)(dp + 56); h4 r2b = *(const h4*)(dp + 58);
#pragma unroll
    for (int o = 0; o < 3; ++o) {
      const h2* w9 = W + o * 9;
      float a0 = acc[o][0], a1 = acc[o][1];
      a0 = dot2(lo2(r0a), w9[0], a0);  a1 = dot2(hi2(r0a), w9[0], a1);
      a0 = dot2(hi2(r0a), w9[1], a0);  a1 = dot2(lo2(r0b), w9[1], a1);
      a0 = dot2(lo2(r0b), w9[2], a0);  a1 = dot2(hi2(r0b), w9[2], a1);
      a0 = dot2(lo2(r1a), w9[3], a0);  a1 = dot2(hi2(r1a), w9[3], a1);
      a0 = dot2(hi2(r1a), w9[4], a0);  a1 = dot2(lo2(r1b), w9[4], a1);
      a0 = dot2(lo2(r1b), w9[5], a0);  a1 = dot2(hi2(r1b), w9[5], a1);
      a0 = dot2(lo2(r2a), w9[6], a0);  a1 = dot2(hi2(r2a), w9[6], a1);
      a0 = dot2(hi2(r2a), w9[7], a0);  a1 = dot2(lo2(r2b), w9[7], a1);
      a0 = dot2(lo2(r2b), w9[8], a0);  a1 = dot2(hi2(r2b), w9[8], a1);
      acc[o][0] = a0; acc[o][1] = a1;
    }
  }
  __syncthreads();                      // Wl dead; cb overlays it
  if (sub == 1) {
#pragma unroll
    for (int o = 0; o < 3; ++o) {
      cb[(o * 288 + r) * 2 + 0] = acc[o][0];
      cb[(o * 288 + r) * 2 + 1] = acc[o][1];
    }
  }
  __syncthreads();
  if (sub == 0) {
    // pair r covers pixels 2r, 2r+1 (p = 24y + 2j = 2r)
    float q0 = acc[0][0] + cb[(0 * 288 + r) * 2 + 0];
    float q1 = acc[0][1] + cb[(0 * 288 + r) * 2 + 1];
    float k0 = acc[1][0] + cb[(1 * 288 + r) * 2 + 0];
    float k1 = acc[1][1] + cb[(1 * 288 + r) * 2 + 1];
    float v0 = acc[2][0] + cb[(2 * 288 + r) * 2 + 0];
    float v1 = acc[2][1] + cb[(2 * 288 + r) * 2 + 1];
    qs[2 * r] = q0; qs[2 * r + 1] = q1;
    kvs[2 * r] = make_float2(k0, v0);
    kvs[2 * r + 1] = make_float2(k1, v1);
  }
  __syncthreads();

  // ---- attention phase: thread tid = pixel tid ----
  float kk = kvs[tid].x;
  float kmax = kk, kmin = kk;
#pragma unroll
  for (int off = 32; off > 0; off >>= 1) {
    kmax = fmaxf(kmax, __shfl_down(kmax, off));
    kmin = fminf(kmin, __shfl_down(kmin, off));
  }
  if ((tid & 63) == 0) { red[tid >> 6] = kmax; red[10 + (tid >> 6)] = kmin; }
  __syncthreads();
  kmax = red[0]; kmin = red[10];
#pragma unroll
  for (int w = 1; w < 9; ++w) {
    kmax = fmaxf(kmax, red[w]); kmin = fminf(kmin, red[10 + w]);
  }
  const float scale_l2e = 0.125f * 1.44269504088896341f;  // 1/sqrt(64)*log2(e)
  const float s = qs[tid] * scale_l2e;
  const float m = (s >= 0.f) ? s * kmax : s * kmin;
  float n0 = 0.f, n1 = 0.f, n2 = 0.f, n3 = 0.f;
  float d0 = 0.f, d1 = 0.f, d2 = 0.f, d3 = 0.f;
  for (int i = 0; i < HW_; i += 4) {
    float4 p0 = *reinterpret_cast<const float4*>(&kvs[i]);
    float4 p1 = *reinterpret_cast<const float4*>(&kvs[i + 2]);
    float e0 = __builtin_amdgcn_exp2f(fmaf(s, p0.x, -m));
    float e1 = __builtin_amdgcn_exp2f(fmaf(s, p0.z, -m));
    float e2 = __builtin_amdgcn_exp2f(fmaf(s, p1.x, -m));
    float e3 = __builtin_amdgcn_exp2f(fmaf(s, p1.z, -m));
    d0 += e0; n0 = fmaf(e0, p0.y, n0);
    d1 += e1; n1 = fmaf(e1, p0.w, n1);
    d2 += e2; n2 = fmaf(e2, p1.y, n2);
    d3 += e3; n3 = fmaf(e3, p1.w, n3);
  }
  float rr = (n0 + n1 + n2 + n3) / (d0 + d1 + d2 + d3);

  const int icp = c >> 1, hc = c & 1;
  _Float16* plane = reinterpret_cast<_Float16*>(outv + ((size_t)(b * 32) + icp) * PPLANE);
  const int yy = tid / 24, xx = tid - yy * 24;
  plane[((yy + 1) * 28 + (xx + 1)) * 2 + hc] = (_Float16)rr;
  if (tid < 100) {  // zero halo (cols 26,27 never read)
    int rrow, e;
    if (tid < 26)      { rrow = 0;            e = tid; }
    else if (tid < 52) { rrow = 25;           e = tid - 26; }
    else if (tid < 76) { rrow = tid - 52 + 1; e = 0; }
    else               { rrow = tid - 76 + 1; e = 25; }
    plane[(rrow * 28 + e) * 2 + hc] = (_Float16)0.f;
  }
}

// ---------------- K3: out conv (OCG=1) + residual + final store ------------
__global__ __launch_bounds__(576)
void conv_out_kernel(const h2* __restrict__ outv, const h2* __restrict__ woh,
                     const float* __restrict__ x, float* __restrict__ out) {
  const int bid = blockIdx.x, tid = threadIdx.x;
  const int b = bid >> 6, oc = bid & 63;
  const int sub = tid / 288;
  const int r = tid - sub * 288;
  const int y = r / 12, x0 = (r % 12) * 2;
  __shared__ __align__(16) char smem[4096];

  h2* Wl = (h2*)smem;                 // [32 icp][12 h2] (9 used)
  for (int j = tid; j < 288; j += 576) {
    int icp = j / 9, rem = j - icp * 9;
    Wl[icp * 12 + rem] = woh[oc * 288 + j];
  }
  __syncthreads();

  float a0 = 0.f, a1 = 0.f;
  const int icp0 = sub * 16;
  for (int i = 0; i < 16; ++i) {
    const int icp = icp0 + i;
    const h2* w9r = Wl + icp * 12;
    h2 W[9];
#pragma unroll
    for (int tt = 0; tt < 9; ++tt) W[tt] = w9r[tt];
    const h2* dp = outv + ((size_t)(b * 32 + icp) * PPLANE + y * 28 + x0);
    h4 r0a = *(const h4*)(dp);      h4 r0b = *(const h4*)(dp + 2);
    h4 r1a = *(const h4*)(dp + 28); h4 r1b = *(const h4*)(dp + 30);
    h4 r2a = *(const h4*)(dp + 56); h4 r2b = *(const h4*)(dp + 58);
    a0 = dot2(lo2(r0a), W[0], a0);  a1 = dot2(hi2(r0a), W[0], a1);
    a0 = dot2(hi2(r0a), W[1], a0);  a1 = dot2(lo2(r0b), W[1], a1);
    a0 = dot2(lo2(r0b), W[2], a0);  a1 = dot2(hi2(r0b), W[2], a1);
    a0 = dot2(lo2(r1a), W[3], a0);  a1 = dot2(hi2(r1a), W[3], a1);
    a0 = dot2(hi2(r1a), W[4], a0);  a1 = dot2(lo2(r1b), W[4], a1);
    a0 = dot2(lo2(r1b), W[5], a0);  a1 = dot2(hi2(r1b), W[5], a1);
    a0 = dot2(lo2(r2a), W[6], a0);  a1 = dot2(hi2(r2a), W[6], a1);
    a0 = dot2(hi2(r2a), W[7], a0);  a1 = dot2(lo2(r2b), W[7], a1);
    a0 = dot2(lo2(r2b), W[8], a0);  a1 = dot2(hi2(r2b), W[8], a1);
  }
  __syncthreads();
  float* cb = (float*)smem;           // [288][2]
  if (sub == 1) { cb[r * 2] = a0; cb[r * 2 + 1] = a1; }
  __syncthreads();
  if (sub == 0) {
    size_t idx = ((size_t)(b * C_IN + oc) * HW_) + y * 24 + x0;
    float2 xr = *reinterpret_cast<const float2*>(x + idx);
    const float inv = 1.f / 4096.f;
    float2 v;
    v.x = fmaf(a0 + cb[r * 2],     inv, xr.x);
    v.y = fmaf(a1 + cb[r * 2 + 1], inv, xr.y);
    *reinterpret_cast<float2*>(out + idx) = v;
  }
}

// ---------------- launch ---------------------------------------------------
extern "C" void kernel_launch(void* const* d_in, const int* in_sizes, int n_in,
                              void* d_out, int out_size, void* d_ws, size_t ws_size,
                              hipStream_t stream) {
  const float* x     = (const float*)d_in[0];
  const float* gamma = (const float*)d_in[1];
  const float* beta  = (const float*)d_in[2];
  const float* w_qkv = (const float*)d_in[3];
  const float* w_out = (const float*)d_in[4];
  float* out = (float*)d_out;

  h2* xh   = (h2*)d_ws;
  h2* wqh  = xh + XH_N;
  h2* woh  = wqh + WQH_N;
  h2* outv = woh + WOH_N;

  stats_pack_kernel<<<256, 256, 0, stream>>>(x, gamma, beta, w_qkv, w_out, xh, wqh, woh);
  qkv_attn_kernel<<<256, 576, 0, stream>>>(xh, wqh, outv);
  conv_out_kernel<<<256, 576, 0, stream>>>(outv, woh, x, out);
}

// Round 8
// 29.040 us; speedup vs baseline: 8.6255x; 1.3642x over previous
//
#include <hip/hip_runtime.h>
#include <math.h>

#define B_SZ 4
#define C_IN 64
#define HW_ 576
#define PPLANE 728                    // 26*28 padded plane of h2 (channel pair)
#define XH_N   (B_SZ * 32 * PPLANE)   // 93184
#define WQH_N  (192 * 32 * 9)         // 55296: ((g*32+icp)*3+o)*9+t, oc=g+64*o
#define WOH_N  (64 * 32 * 9)          // 18432: (oc*32+icp)*9+t

typedef _Float16 h2 __attribute__((ext_vector_type(2)));
typedef _Float16 h4 __attribute__((ext_vector_type(4)));

static __device__ __forceinline__ h2 lo2(h4 v) { return __builtin_shufflevector(v, v, 0, 1); }
static __device__ __forceinline__ h2 hi2(h4 v) { return __builtin_shufflevector(v, v, 2, 3); }

static __device__ __forceinline__ float dot2(h2 a, h2 b, float c) {
#if __has_builtin(__builtin_amdgcn_fdot2)
  return __builtin_amdgcn_fdot2(a, b, c, false);
#else
  return c + (float)a.x * (float)b.x + (float)a.y * (float)b.y;
#endif
}

static __device__ __forceinline__ float frcp(float d) {
#if __has_builtin(__builtin_amdgcn_rcpf)
  return __builtin_amdgcn_rcpf(d);
#else
  return 1.0f / d;
#endif
}

// ---------------- K1: BN stats (redundant per block) + pack x & weights ----
__global__ __launch_bounds__(256)
void stats_pack_kernel(const float* __restrict__ x, const float* __restrict__ gamma,
                       const float* __restrict__ beta, const float* __restrict__ wq,
                       const float* __restrict__ wo, h2* __restrict__ xh,
                       h2* __restrict__ wqh, h2* __restrict__ woh) {
  const int bid = blockIdx.x, tid = threadIdx.x;
  if (bid < 128) {
    const int icp = bid & 31, b = bid >> 5;
    __shared__ float rs[4], rss[4], ab[4];
    const int c = icp * 2 + (tid >> 7);
    float s = 0.f, ss = 0.f;
    for (int i = (tid & 127); i < B_SZ * HW_; i += 128) {
      int b2 = i / HW_, px = i - b2 * HW_;
      float v = x[(b2 * C_IN + c) * HW_ + px];
      s += v; ss = fmaf(v, v, ss);
    }
#pragma unroll
    for (int off = 32; off > 0; off >>= 1) {
      s += __shfl_down(s, off); ss += __shfl_down(ss, off);
    }
    if ((tid & 63) == 0) { rs[tid >> 6] = s; rss[tid >> 6] = ss; }
    __syncthreads();
    if (tid < 2) {
      float S = rs[tid * 2] + rs[tid * 2 + 1], SS = rss[tid * 2] + rss[tid * 2 + 1];
      const float inv_n = 1.f / (B_SZ * HW_);
      float mean = S * inv_n;
      float var  = SS * inv_n - mean * mean;
      float a = rsqrtf(var + 1e-5f) * gamma[icp * 2 + tid];
      ab[tid * 2] = a;
      ab[tid * 2 + 1] = fmaf(-mean, a, beta[icp * 2 + tid]);
    }
    __syncthreads();
    const float a0 = ab[0], b0 = ab[1], a1 = ab[2], b1 = ab[3];
    h2* plane = xh + (size_t)(b * 32 + icp) * PPLANE;
    const float* src0 = x + (size_t)(b * C_IN + icp * 2) * HW_;
    for (int e = tid; e < PPLANE; e += 256) {
      int rrow = e / 28, ecol = e - rrow * 28;
      int yy = rrow - 1, xx = ecol - 1;
      float f0 = 0.f, f1 = 0.f;
      if ((unsigned)yy < 24u && (unsigned)xx < 24u) {
        f0 = fmaf(src0[yy * 24 + xx],       a0, b0);
        f1 = fmaf(src0[HW_ + yy * 24 + xx], a1, b1);
      }
      h2 v; v.x = (_Float16)f0; v.y = (_Float16)f1;
      plane[e] = v;
    }
  } else {
    const int base = (bid - 128) * 576;
    for (int t = base + tid; t < base + 576; t += 256) {
      if (t < WQH_N) {
        int tt = t % 9; int r = t / 9;
        int o = r % 3; r /= 3;
        int icp = r % 32; int g = r / 32;
        int oc = g + 64 * o, ic = icp * 2;   // q/k/v of channel g in one block
        h2 v;
        v.x = (_Float16)wq[(oc * C_IN + ic) * 9 + tt];
        v.y = (_Float16)wq[(oc * C_IN + ic + 1) * 9 + tt];
        wqh[t] = v;
      } else {
        int t0 = t - WQH_N;
        int tt = t0 % 9; int r = t0 / 9;
        int icp = r % 32; int oc = r / 32;
        int ic = icp * 2;
        h2 v;  // scale 4096: dodge f16 subnormals (w_out ~ 7e-5)
        v.x = (_Float16)(wo[(oc * C_IN + ic) * 9 + tt] * 4096.f);
        v.y = (_Float16)(wo[(oc * C_IN + ic + 1) * 9 + tt] * 4096.f);
        woh[t0] = v;
      }
    }
  }
}

// ---------------- K2: fused qkv conv + barycentric rank-1 attention --------
// Conv: 576 thr = 2 K-halves x 288 pixel-pairs, oc = {c, 64+c, 128+c}.
// Attention: out(p)=f(s_p)/g(s_p), f(s)=Σ v_i 2^{s k_i}, g(s)=Σ 2^{s k_i};
// approximated by 9-node Chebyshev barycentric on [smin,smax] (|s·k| ≤ ~3
// -> interp error ~1e-6 rel; threshold budget is ~1e-2). Ratio form cancels
// the barycentric normalization; s≈node limits to f_j/g_j (clamped).
__global__ __launch_bounds__(576)
void qkv_attn_kernel(const h2* __restrict__ xh, const h2* __restrict__ wqh,
                     h2* __restrict__ outv) {
  const int bid = blockIdx.x, tid = threadIdx.x;
  const int b = bid >> 6, c = bid & 63;
  const int sub = tid / 288;
  const int r = tid - sub * 288;
  const int y = r / 12, x0 = (r % 12) * 2;

  __shared__ __align__(16) char smem[14560];
  h2*    Wl  = (h2*)smem;               // [32][28] h2 (conv phase)
  float* cb  = (float*)smem;            // [3][288][2] f32 (combine)
  float2* kvs = (float2*)(smem + 6912); // 576 float2
  float* qs  = (float*)(smem + 11520);  // 576 f32 (pre-scaled s values)
  float* red = (float*)(smem + 13824);  // minmax (20) then FG partials (162)
  float* FGf = (float*)(smem + 14472);  // 18 finals

  for (int j = tid; j < 864; j += 576) {
    int icp = j / 27, rem = j - icp * 27;
    Wl[icp * 28 + rem] = wqh[c * 864 + j];
  }
  __syncthreads();

  float acc[3][2] = {{0.f, 0.f}, {0.f, 0.f}, {0.f, 0.f}};
  const int icp0 = sub * 16;
  for (int i = 0; i < 16; ++i) {
    const int icp = icp0 + i;
    const h2* wrow = Wl + icp * 28;
    h2 W[27];
#pragma unroll
    for (int tt = 0; tt < 27; ++tt) W[tt] = wrow[tt];
    const h2* dp = xh + ((size_t)(b * 32 + icp) * PPLANE + y * 28 + x0);
    h4 r0a = *(const h4*)(dp);      h4 r0b = *(const h4*)(dp + 2);
    h4 r1a = *(const h4*)(dp + 28); h4 r1b = *(const h4*)(dp + 30);
    h4 r2a = *(const h4*)(dp + 56); h4 r2b = *(const h4*)(dp + 58);
#pragma unroll
    for (int o = 0; o < 3; ++o) {
      const h2* w9 = W + o * 9;
      float a0 = acc[o][0], a1 = acc[o][1];
      a0 = dot2(lo2(r0a), w9[0], a0);  a1 = dot2(hi2(r0a), w9[0], a1);
      a0 = dot2(hi2(r0a), w9[1], a0);  a1 = dot2(lo2(r0b), w9[1], a1);
      a0 = dot2(lo2(r0b), w9[2], a0);  a1 = dot2(hi2(r0b), w9[2], a1);
      a0 = dot2(lo2(r1a), w9[3], a0);  a1 = dot2(hi2(r1a), w9[3], a1);
      a0 = dot2(hi2(r1a), w9[4], a0);  a1 = dot2(lo2(r1b), w9[4], a1);
      a0 = dot2(lo2(r1b), w9[5], a0);  a1 = dot2(hi2(r1b), w9[5], a1);
      a0 = dot2(lo2(r2a), w9[6], a0);  a1 = dot2(hi2(r2a), w9[6], a1);
      a0 = dot2(hi2(r2a), w9[7], a0);  a1 = dot2(lo2(r2b), w9[7], a1);
      a0 = dot2(lo2(r2b), w9[8], a0);  a1 = dot2(hi2(r2b), w9[8], a1);
      acc[o][0] = a0; acc[o][1] = a1;
    }
  }
  __syncthreads();                      // Wl dead; cb overlays it
  if (sub == 1) {
#pragma unroll
    for (int o = 0; o < 3; ++o) {
      cb[(o * 288 + r) * 2 + 0] = acc[o][0];
      cb[(o * 288 + r) * 2 + 1] = acc[o][1];
    }
  }
  __syncthreads();
  const float scale_l2e = 0.125f * 1.44269504088896341f;  // 1/sqrt(64)*log2(e)
  if (sub == 0) {
    float q0 = acc[0][0] + cb[(0 * 288 + r) * 2 + 0];
    float q1 = acc[0][1] + cb[(0 * 288 + r) * 2 + 1];
    float k0 = acc[1][0] + cb[(1 * 288 + r) * 2 + 0];
    float k1 = acc[1][1] + cb[(1 * 288 + r) * 2 + 1];
    float v0 = acc[2][0] + cb[(2 * 288 + r) * 2 + 0];
    float v1 = acc[2][1] + cb[(2 * 288 + r) * 2 + 1];
    qs[2 * r] = q0 * scale_l2e; qs[2 * r + 1] = q1 * scale_l2e;
    kvs[2 * r] = make_float2(k0, v0);
    kvs[2 * r + 1] = make_float2(k1, v1);
  }
  __syncthreads();

  // ---- attention phase (thread tid = pixel tid) ----
  const float s = qs[tid];
  float smax = s, smin = s;
#pragma unroll
  for (int off = 32; off > 0; off >>= 1) {
    smax = fmaxf(smax, __shfl_down(smax, off));
    smin = fminf(smin, __shfl_down(smin, off));
  }
  const int wid = tid >> 6;
  if ((tid & 63) == 0) { red[wid] = smax; red[10 + wid] = smin; }
  __syncthreads();
  smax = red[0]; smin = red[10];
#pragma unroll
  for (int w = 1; w < 9; ++w) {
    smax = fmaxf(smax, red[w]); smin = fminf(smin, red[10 + w]);
  }
  __syncthreads();                      // red reused for FG partials below
  const float cc = 0.5f * (smax + smin);
  const float rr = fmaxf(0.5f * (smax - smin), 1e-6f);
  // Chebyshev 1st-kind nodes/weights, theta_j=(2j+1)*10deg
  const float COS[9] = { 0.98480775f,  0.86602540f,  0.64278761f,  0.34202014f, 0.f,
                        -0.34202014f, -0.64278761f, -0.86602540f, -0.98480775f };
  const float WJ[9]  = { 0.17364818f, -0.5f,  0.76604444f, -0.93969262f, 1.f,
                        -0.93969262f, 0.76604444f, -0.5f, 0.17364818f };
  float xj[9];
#pragma unroll
  for (int j = 0; j < 9; ++j) xj[j] = fmaf(rr, COS[j], cc);

  const float kk = kvs[tid].x, vv = kvs[tid].y;
  float fj[9], gj[9];
#pragma unroll
  for (int j = 0; j < 9; ++j) {
    float E = __builtin_amdgcn_exp2f(xj[j] * kk);
    gj[j] = E; fj[j] = E * vv;
  }
#pragma unroll
  for (int off = 32; off > 0; off >>= 1) {
#pragma unroll
    for (int j = 0; j < 9; ++j) {
      fj[j] += __shfl_down(fj[j], off);
      gj[j] += __shfl_down(gj[j], off);
    }
  }
  if ((tid & 63) == 0) {
#pragma unroll
    for (int j = 0; j < 9; ++j) {
      red[wid * 18 + j] = fj[j];
      red[wid * 18 + 9 + j] = gj[j];
    }
  }
  __syncthreads();
  if (tid < 18) {
    float sum = 0.f;
#pragma unroll
    for (int w = 0; w < 9; ++w) sum += red[w * 18 + tid];
    FGf[tid] = sum;
  }
  __syncthreads();

  float num = 0.f, den = 0.f;
#pragma unroll
  for (int j = 0; j < 9; ++j) {
    float d = s - xj[j];
    d = copysignf(fmaxf(fabsf(d), 1e-7f), d);
    float mu = WJ[j] * frcp(d);
    num = fmaf(mu, FGf[j], num);
    den = fmaf(mu, FGf[9 + j], den);
  }
  float outval = num / den;

  const int icp = c >> 1, hc = c & 1;
  _Float16* plane = reinterpret_cast<_Float16*>(outv + ((size_t)(b * 32) + icp) * PPLANE);
  const int yy = tid / 24, xx = tid - yy * 24;
  plane[((yy + 1) * 28 + (xx + 1)) * 2 + hc] = (_Float16)outval;
  if (tid < 100) {  // zero halo (cols 26,27 never read)
    int rrow, e;
    if (tid < 26)      { rrow = 0;            e = tid; }
    else if (tid < 52) { rrow = 25;           e = tid - 26; }
    else if (tid < 76) { rrow = tid - 52 + 1; e = 0; }
    else               { rrow = tid - 76 + 1; e = 25; }
    plane[(rrow * 28 + e) * 2 + hc] = (_Float16)0.f;
  }
}

// ---------------- K3: out conv (OCG=1) + residual + final store ------------
__global__ __launch_bounds__(576)
void conv_out_kernel(const h2* __restrict__ outv, const h2* __restrict__ woh,
                     const float* __restrict__ x, float* __restrict__ out) {
  const int bid = blockIdx.x, tid = threadIdx.x;
  const int b = bid >> 6, oc = bid & 63;
  const int sub = tid / 288;
  const int r = tid - sub * 288;
  const int y = r / 12, x0 = (r % 12) * 2;
  __shared__ __align__(16) char smem[4096];

  h2* Wl = (h2*)smem;                 // [32 icp][12 h2] (9 used)
  for (int j = tid; j < 288; j += 576) {
    int icp = j / 9, rem = j - icp * 9;
    Wl[icp * 12 + rem] = woh[oc * 288 + j];
  }
  __syncthreads();

  float a0 = 0.f, a1 = 0.f;
  const int icp0 = sub * 16;
  for (int i = 0; i < 16; ++i) {
    const int icp = icp0 + i;
    const h2* w9r = Wl + icp * 12;
    h2 W[9];
#pragma unroll
    for (int tt = 0; tt < 9; ++tt) W[tt] = w9r[tt];
    const h2* dp = outv + ((size_t)(b * 32 + icp) * PPLANE + y * 28 + x0);
    h4 r0a = *(const h4*)(dp);      h4 r0b = *(const h4*)(dp + 2);
    h4 r1a = *(const h4*)(dp + 28); h4 r1b = *(const h4*)(dp + 30);
    h4 r2a = *(const h4*)(dp + 56); h4 r2b = *(const h4*)(dp + 58);
    a0 = dot2(lo2(r0a), W[0], a0);  a1 = dot2(hi2(r0a), W[0], a1);
    a0 = dot2(hi2(r0a), W[1], a0);  a1 = dot2(lo2(r0b), W[1], a1);
    a0 = dot2(lo2(r0b), W[2], a0);  a1 = dot2(hi2(r0b), W[2], a1);
    a0 = dot2(lo2(r1a), W[3], a0);  a1 = dot2(hi2(r1a), W[3], a1);
    a0 = dot2(hi2(r1a), W[4], a0);  a1 = dot2(lo2(r1b), W[4], a1);
    a0 = dot2(lo2(r1b), W[5], a0);  a1 = dot2(hi2(r1b), W[5], a1);
    a0 = dot2(lo2(r2a), W[6], a0);  a1 = dot2(hi2(r2a), W[6], a1);
    a0 = dot2(hi2(r2a), W[7], a0);  a1 = dot2(lo2(r2b), W[7], a1);
    a0 = dot2(lo2(r2b), W[8], a0);  a1 = dot2(hi2(r2b), W[8], a1);
  }
  __syncthreads();
  float* cb = (float*)smem;           // [288][2]
  if (sub == 1) { cb[r * 2] = a0; cb[r * 2 + 1] = a1; }
  __syncthreads();
  if (sub == 0) {
    size_t idx = ((size_t)(b * C_IN + oc) * HW_) + y * 24 + x0;
    float2 xr = *reinterpret_cast<const float2*>(x + idx);
    const float inv = 1.f / 4096.f;
    float2 v;
    v.x = fmaf(a0 + cb[r * 2],     inv, xr.x);
    v.y = fmaf(a1 + cb[r * 2 + 1], inv, xr.y);
    *reinterpret_cast<float2*>(out + idx) = v;
  }
}

// ---------------- launch ---------------------------------------------------
extern "C" void kernel_launch(void* const* d_in, const int* in_sizes, int n_in,
                              void* d_out, int out_size, void* d_ws, size_t ws_size,
                              hipStream_t stream) {
  const float* x     = (const float*)d_in[0];
  const float* gamma = (const float*)d_in[1];
  const float* beta  = (const float*)d_in[2];
  const float* w_qkv = (const float*)d_in[3];
  const float* w_out = (const float*)d_in[4];
  float* out = (float*)d_out;

  h2* xh   = (h2*)d_ws;
  h2* wqh  = xh + XH_N;
  h2* woh  = wqh + WQH_N;
  h2* outv = woh + WOH_N;

  stats_pack_kernel<<<256, 256, 0, stream>>>(x, gamma, beta, w_qkv, w_out, xh, wqh, woh);
  qkv_attn_kernel<<<256, 576, 0, stream>>>(xh, wqh, outv);
  conv_out_kernel<<<256, 576, 0, stream>>>(outv, woh, x, out);
}